// Round 5
// baseline (603.204 us; speedup 1.0000x reference)
//
#include <hip/hip_runtime.h>

// Problem constants (from reference)
#define BB 16
#define SS 4096
#define HH 1024
#define NW 2048          // N (max word tokens)
#define DWW 50           // glove dim
#define OUTW (HH + DWW)  // 1074

// ws layout: accum (B*H u32, monotonic-keyed prefix ctx max), lwacc (B*64 u32)
#define WS_ACC_OFF 0
#define WS_LW_OFF  (BB * HH * 4)
#define INIT_WORDS (BB * HH + BB * 64)  // 17408

// Monotonic uint key: f1 < f2  <=>  ukey(f1) < ukey(f2). All finite inputs map
// to keys > 0, so a 0-initialized accumulator acts as -inf.
__device__ __forceinline__ unsigned ukey(float f) {
  unsigned u = __float_as_uint(f);
  return (u & 0x80000000u) ? ~u : (u | 0x80000000u);
}
__device__ __forceinline__ float ukey_dec(unsigned k) {
  return __uint_as_float((k & 0x80000000u) ? (k ^ 0x80000000u) : ~k);
}

__global__ __launch_bounds__(256) void k_init(unsigned* __restrict__ acc) {
  acc[blockIdx.x * 256 + threadIdx.x] = 0u;  // grid(68): exactly INIT_WORDS
}

// first index s in [0,S) with segb[s] >= x  (segb sorted ascending)
__device__ __forceinline__ int lower_bound_seg(const int* __restrict__ segb, int x) {
  int lo = 0, hi = SS;
  while (lo < hi) {
    int mid = (lo + hi) >> 1;
    if (segb[mid] < x) lo = mid + 1; else hi = mid;
  }
  return lo;
}

__global__ __launch_bounds__(256) void k_main(
    const float* __restrict__ ctx, const float* __restrict__ wemb,
    const int* __restrict__ seg, const int* __restrict__ ns,
    unsigned* __restrict__ accum, unsigned* __restrict__ lwacc,
    float* __restrict__ out) {
  const int w = blockIdx.x;
  const int b = blockIdx.y;
  const int t = threadIdx.x;
  const int nsb = ns[b];
  float* orow = out + ((size_t)b * NW + w) * OUTW;

  if (w >= nsb) {  // padding word position -> zero vector (1074 = 537 float2)
    float2* o2 = reinterpret_cast<float2*>(orow);
    for (int j = t; j < OUTW / 2; j += 256) o2[j] = make_float2(0.0f, 0.0f);
    return;
  }
  if (w == nsb - 1) return;  // last (doc) token written by k_last

  // span of word w via binary search on sorted seg (uniform, L2-hot)
  const int* segb = seg + b * SS;
  const int s0 = lower_bound_seg(segb, w);
  const int s1 = lower_bound_seg(segb, w + 1);
  const int lim = nsb - 1;  // subwords [0, lim) feed last_ctx

  float4 m  = make_float4(-INFINITY, -INFINITY, -INFINITY, -INFINITY);
  float4 mp = m;  // prefix-restricted max (rows s < lim)
  const float* cb = ctx + (size_t)b * SS * HH;
  for (int s = s0; s < s1; ++s) {
    const float4 v = *reinterpret_cast<const float4*>(cb + (size_t)s * HH + 4 * t);
    m.x = fmaxf(m.x, v.x); m.y = fmaxf(m.y, v.y);
    m.z = fmaxf(m.z, v.z); m.w = fmaxf(m.w, v.w);
    if (s < lim) {
      mp.x = fmaxf(mp.x, v.x); mp.y = fmaxf(mp.y, v.y);
      mp.z = fmaxf(mp.z, v.z); mp.w = fmaxf(mp.w, v.w);
    }
  }

  // Store H part (rows are only 8B aligned; use float2)
  float2* o2 = reinterpret_cast<float2*>(orow);
  o2[2 * t]     = make_float2(m.x, m.y);
  o2[2 * t + 1] = make_float2(m.z, m.w);

  // DW tail + last_w atomic contribution
  if (t < DWW) {
    const float v = wemb[((size_t)b * NW + w) * DWW + t];
    orow[HH + t] = v;
    atomicMax(&lwacc[b * 64 + t], ukey(v));
  }

  // prefix ctx contribution (only blocks whose span intersects [0, lim))
  if (s0 < lim) {
    unsigned* ab = accum + b * HH;
    atomicMax(&ab[4 * t + 0], ukey(mp.x));
    atomicMax(&ab[4 * t + 1], ukey(mp.y));
    atomicMax(&ab[4 * t + 2], ukey(mp.z));
    atomicMax(&ab[4 * t + 3], ukey(mp.w));
  }
}

__global__ __launch_bounds__(1024) void k_last(
    const float* __restrict__ wemb, const int* __restrict__ ns,
    const unsigned* __restrict__ accum, const unsigned* __restrict__ lwacc,
    float* __restrict__ out) {
  const int b = blockIdx.x;
  const int t = threadIdx.x;
  const int nsb = ns[b];
  float* orow = out + ((size_t)b * NW + (nsb - 1)) * OUTW;

  orow[t] = ukey_dec(accum[b * HH + t]);  // last_ctx = prefix max

  if (t < DWW) {
    // last_w includes word nsb-1's own word_emb row (wmask = wpos < ns)
    float v = ukey_dec(lwacc[b * 64 + t]);
    v = fmaxf(v, wemb[((size_t)b * NW + (nsb - 1)) * DWW + t]);
    orow[HH + t] = v;
  }
}

extern "C" void kernel_launch(void* const* d_in, const int* in_sizes, int n_in,
                              void* d_out, int out_size, void* d_ws, size_t ws_size,
                              hipStream_t stream) {
  const float* ctx  = (const float*)d_in[0];  // [B,S,H]
  const float* wemb = (const float*)d_in[1];  // [B,N,DW]
  const int*   seg  = (const int*)d_in[2];    // [B,S]
  const int*   ns   = (const int*)d_in[3];    // [B]
  float* out = (float*)d_out;

  char* ws = (char*)d_ws;
  unsigned* accum = (unsigned*)(ws + WS_ACC_OFF);
  unsigned* lwacc = (unsigned*)(ws + WS_LW_OFF);

  k_init<<<dim3(INIT_WORDS / 256), dim3(256), 0, stream>>>(accum);
  k_main<<<dim3(NW, BB), dim3(256), 0, stream>>>(ctx, wemb, seg, ns, accum, lwacc, out);
  k_last<<<dim3(BB), dim3(1024), 0, stream>>>(wemb, ns, accum, lwacc, out);
}

// Round 9
// 442.729 us; speedup vs baseline: 1.3625x; 1.3625x over previous
//
#include <hip/hip_runtime.h>

// Problem constants (from reference)
#define BB 16
#define SS 4096
#define HH 1024
#define NW 2048          // N (max word tokens)
#define DWW 50           // glove dim
#define OUTW (HH + DWW)  // 1074
#define CHUNKS 32
#define CHUNK 64         // CHUNKS*CHUNK = 2048 >= max(ns-1)

// ws layout (plain float stores, no init needed — every read slot is written):
//   partial : [B][CHUNKS][HH]  ctx prefix chunk maxes
//   lastwp  : [B][CHUNKS][64]  word_emb chunk maxes (dims 0..49 valid)
#define WS_PARTIAL_OFF 0
#define WS_LASTWP_OFF  (BB * CHUNKS * HH * 4)

// first index s in [0,S) with segb[s] >= x  (segb sorted ascending)
__device__ __forceinline__ int lower_bound_seg(const int* __restrict__ segb, int x) {
  int lo = 0, hi = SS;
  while (lo < hi) {
    int mid = (lo + hi) >> 1;
    if (segb[mid] < x) lo = mid + 1; else hi = mid;
  }
  return lo;
}

// grid (NW + CHUNKS, B):
//   blockIdx.x <  NW : word block (segment max -> output row)
//   blockIdx.x >= NW : chunk block c = blockIdx.x - NW (prefix + last_w partials)
__global__ __launch_bounds__(256) void k_main(
    const float* __restrict__ ctx, const float* __restrict__ wemb,
    const int* __restrict__ seg, const int* __restrict__ ns,
    float* __restrict__ partial, float* __restrict__ lastwp,
    float* __restrict__ out) {
  const int b = blockIdx.y;
  const int t = threadIdx.x;
  const int nsb = ns[b];
  const float* cb = ctx + (size_t)b * SS * HH;

  if (blockIdx.x >= NW) {  // ---- chunk block: partials into ws ----
    const int c = blockIdx.x - NW;

    // last_w partial over words [c*64, c*64+64) ∩ [0, nsb)  (includes nsb-1)
    {
      const int d = t & 63;
      const int r = t >> 6;  // 0..3
      float m = -INFINITY;
      if (d < DWW) {
        const float* wb = wemb + (size_t)b * NW * DWW;
        for (int i = 0; i < CHUNK / 4; ++i) {
          const int w = c * CHUNK + 4 * i + r;
          if (w < nsb) m = fmaxf(m, wb[(size_t)w * DWW + d]);
        }
      }
      __shared__ float red[256];
      red[t] = m;
      __syncthreads();
      if (r == 0 && d < DWW) {
        lastwp[((size_t)b * CHUNKS + c) * 64 + d] =
            fmaxf(fmaxf(red[d], red[64 + d]), fmaxf(red[128 + d], red[192 + d]));
      }
    }

    // ctx prefix partial: rows [c*64, c*64+64) ∩ [0, nsb-1)
    {
      const int s0 = c * CHUNK;
      const int s1 = min(s0 + CHUNK, nsb - 1);
      float4 m = make_float4(-INFINITY, -INFINITY, -INFINITY, -INFINITY);
      for (int s = s0; s < s1; ++s) {
        const float4 v = *reinterpret_cast<const float4*>(cb + (size_t)s * HH + 4 * t);
        m.x = fmaxf(m.x, v.x); m.y = fmaxf(m.y, v.y);
        m.z = fmaxf(m.z, v.z); m.w = fmaxf(m.w, v.w);
      }
      float4* p = reinterpret_cast<float4*>(partial + ((size_t)b * CHUNKS + c) * HH);
      p[t] = m;
    }
    return;
  }

  // ---- word block ----
  const int w = blockIdx.x;
  float* orow = out + ((size_t)b * NW + w) * OUTW;

  if (w >= nsb) {  // padding word position -> zero vector (1074 = 537 float2)
    float2* o2 = reinterpret_cast<float2*>(orow);
    for (int j = t; j < OUTW / 2; j += 256) o2[j] = make_float2(0.0f, 0.0f);
    return;
  }
  if (w == nsb - 1) return;  // last (doc) token written by k_last

  // span of word w via binary search on sorted seg (uniform across threads)
  const int* segb = seg + b * SS;
  const int s0 = lower_bound_seg(segb, w);
  const int s1 = lower_bound_seg(segb, w + 1);

  float4 m = make_float4(-INFINITY, -INFINITY, -INFINITY, -INFINITY);
  for (int s = s0; s < s1; ++s) {
    const float4 v = *reinterpret_cast<const float4*>(cb + (size_t)s * HH + 4 * t);
    m.x = fmaxf(m.x, v.x); m.y = fmaxf(m.y, v.y);
    m.z = fmaxf(m.z, v.z); m.w = fmaxf(m.w, v.w);
  }

  // Store H part (rows are only 8B aligned; use float2)
  float2* o2 = reinterpret_cast<float2*>(orow);
  o2[2 * t]     = make_float2(m.x, m.y);
  o2[2 * t + 1] = make_float2(m.z, m.w);

  // DW tail: copy word_emb row
  if (t < DWW) orow[HH + t] = wemb[((size_t)b * NW + w) * DWW + t];
}

// grid (B), 1024 threads: reduce the 32 chunk partials -> last word row
__global__ __launch_bounds__(1024) void k_last(
    const int* __restrict__ ns, const float* __restrict__ partial,
    const float* __restrict__ lastwp, float* __restrict__ out) {
  const int b = blockIdx.x;
  const int t = threadIdx.x;
  const int nsb = ns[b];
  float* orow = out + ((size_t)b * NW + (nsb - 1)) * OUTW;

  float m = -INFINITY;
  const float* p = partial + (size_t)b * CHUNKS * HH;
  for (int c = 0; c < CHUNKS; ++c) m = fmaxf(m, p[c * HH + t]);
  orow[t] = m;  // last_ctx = prefix max over subwords [0, nsb-1)

  if (t < DWW) {
    float v = -INFINITY;
    const float* lp = lastwp + (size_t)b * CHUNKS * 64;
    for (int c = 0; c < CHUNKS; ++c) v = fmaxf(v, lp[c * 64 + t]);
    orow[HH + t] = v;  // last_w = max over word_emb[b, 0:nsb)
  }
}

extern "C" void kernel_launch(void* const* d_in, const int* in_sizes, int n_in,
                              void* d_out, int out_size, void* d_ws, size_t ws_size,
                              hipStream_t stream) {
  const float* ctx  = (const float*)d_in[0];  // [B,S,H]
  const float* wemb = (const float*)d_in[1];  // [B,N,DW]
  const int*   seg  = (const int*)d_in[2];    // [B,S]
  const int*   ns   = (const int*)d_in[3];    // [B]
  float* out = (float*)d_out;

  char* ws = (char*)d_ws;
  float* partial = (float*)(ws + WS_PARTIAL_OFF);
  float* lastwp  = (float*)(ws + WS_LASTWP_OFF);

  k_main<<<dim3(NW + CHUNKS, BB), dim3(256), 0, stream>>>(ctx, wemb, seg, ns, partial, lastwp, out);
  k_last<<<dim3(BB), dim3(1024), 0, stream>>>(ns, partial, lastwp, out);
}